// Round 9
// baseline (22211.568 us; speedup 1.0000x reference)
//
#include <hip/hip_runtime.h>
#include <math.h>

#define TT 2048
#define DIN 64
#define HH 256

typedef __attribute__((ext_vector_type(8))) short bf16x8;
typedef __attribute__((ext_vector_type(4))) float f32x4;
typedef __attribute__((ext_vector_type(4))) unsigned u32x4;
typedef unsigned short u16;
typedef unsigned u32t;

// ---- LDS offsets (shorts). Swizzled fragment staging, no padding. ----
#define OFF_W0LO 0                    // [10 kt][4 wv][64 lane][8]  = 20480
#define OFF_W1LO 20480                // [16 kt][4 wv][64 lane][8]  = 32768
#define OFF_H    53248                // 4 planes x (16 rows x 256) = 16384
#define OFF_X    69632                // 2 par x (hi 1024 + lo 1024) = 4096
#define SH_SHORTS 73728
#define LDS_BYTES (SH_SHORTS*2)       // 147456 B

__device__ __forceinline__ u16 f2bf(float f){
    u32t u = __builtin_bit_cast(u32t, f);
    u += 0x7fffu + ((u >> 16) & 1u);   // RNE
    return (u16)(u >> 16);
}
__device__ __forceinline__ float bf2f(u16 h){
    u32t u = ((u32t)h) << 16;
    return __builtin_bit_cast(float, u);
}
__device__ __forceinline__ float sigf(float v){ return 1.0f/(1.0f+__expf(-v)); }
__device__ __forceinline__ float tanh_fast(float v){
    float x = fminf(fmaxf(v, -20.f), 20.f);
    float t = __expf(2.f*x);
    return (t - 1.f) / (t + 1.f);
}
__device__ __forceinline__ void split8(float4 a, float4 b, bf16x8& hi, bf16x8& lo){
    float v[8] = {a.x,a.y,a.z,a.w,b.x,b.y,b.z,b.w};
    #pragma unroll
    for (int j=0;j<8;++j){
        u16 h = f2bf(v[j]);
        hi[j] = (short)h;
        lo[j] = (short)f2bf(v[j] - bf2f(h));
    }
}

// r7-proven flag barrier: release store to own slot, parallel acquire poll.
__device__ __forceinline__ void group_barrier(u32t* flg, int wgin, unsigned epoch){
    __syncthreads();
    if (threadIdx.x == 0)
        __hip_atomic_store(flg + wgin*16, epoch, __ATOMIC_RELEASE, __HIP_MEMORY_SCOPE_AGENT);
    if (threadIdx.x < 16){
        while (__hip_atomic_load(flg + threadIdx.x*16, __ATOMIC_ACQUIRE, __HIP_MEMORY_SCOPE_AGENT) < epoch)
            __builtin_amdgcn_s_sleep(1);
    }
    __syncthreads();
}

// 4-lane gate recombine: lane gate b = c&3; cols = unit-major, gate-minor.
__device__ __forceinline__ void gates4(int b, float v, float& gi, float& gf, float& gg, float& go){
    int vi = __builtin_bit_cast(int, v);
    float f1 = __builtin_bit_cast(float, __builtin_amdgcn_ds_swizzle(vi, 0x041F)); // lane^1
    float f2 = __builtin_bit_cast(float, __builtin_amdgcn_ds_swizzle(vi, 0x081F)); // lane^2
    float f3 = __builtin_bit_cast(float, __builtin_amdgcn_ds_swizzle(vi, 0x0C1F)); // lane^3
    gi = (b==0)?v :(b==1)?f1:(b==2)?f2:f3;
    gf = (b==0)?f1:(b==1)?v :(b==2)?f3:f2;
    gg = (b==0)?f2:(b==1)?f3:(b==2)?v :f1;
    go = (b==0)?f3:(b==1)?f2:(b==2)?f1:v;
}

#define MFMA16(a,b,c_) __builtin_amdgcn_mfma_f32_16x16x32_bf16(a,b,c_,0,0,0)

__global__ __launch_bounds__(256, 1)
void lstm_v9(const float* __restrict__ x,
             const float* __restrict__ Wih0, const float* __restrict__ Whh0,
             const float* __restrict__ bih0, const float* __restrict__ bhh0,
             const float* __restrict__ Wih1, const float* __restrict__ Whh1,
             const float* __restrict__ bih1, const float* __restrict__ bhh1,
             const float* __restrict__ Wd,   const float* __restrict__ bd,
             float* __restrict__ out, u16* __restrict__ hb,
             u32t* __restrict__ flags)
{
    extern __shared__ short sh[];

    const int tid = threadIdx.x;
    const int w   = blockIdx.x;
    const int grp  = w & 15;       // row-group 0..15 (16 rows each)
    const int wgin = w >> 4;       // WG within group 0..15 (16 units each)
    const int grpbase = grp * 16;
    const int ubase   = wgin * 16;

    u32t* flg = flags + grp * 256;

    // h planes (u16): h0hi(0) h0lo(131072) h1hi(262144) h1lo(393216), +parity*65536

    const int l  = tid & 63;
    const int wv = tid >> 6;        // wave 0..3 -> units ubase+wv*4 .. +3
    const int c  = l & 15, ks = l >> 4;
    const int cx = c & 7;
    const int b  = c & 3;           // gate (0=i,1=f,2=g,3=o)
    const int un = ubase + wv*4 + (c >> 2);   // hidden unit of this col
    const int G  = b*HH + un;                  // gate-row in weights

    // ---- stationary HI weight fragments in registers ----
    bf16x8 w0h[10];
    #pragma unroll
    for (int kt = 0; kt < 10; ++kt){
        int k = kt*32 + ks*8;
        const float* p = (k < 64) ? (Wih0 + (size_t)G*DIN + k)
                                  : (Whh0 + (size_t)G*HH + (k - 64));
        bf16x8 hi_, lo_; split8(*(const float4*)p, *(const float4*)(p+4), hi_, lo_);
        w0h[kt] = hi_;
    }
    bf16x8 w1h[16];
    #pragma unroll
    for (int kt = 0; kt < 16; ++kt){
        int k = kt*32 + ks*8;
        const float* p = (k < 256) ? (Wih1 + (size_t)G*HH + k)
                                   : (Whh1 + (size_t)G*HH + (k - 256));
        bf16x8 hi_, lo_; split8(*(const float4*)p, *(const float4*)(p+4), hi_, lo_);
        w1h[kt] = hi_;
    }
    const float bs0 = bih0[G] + bhh0[G];
    const float bs1 = bih1[G] + bhh1[G];

    // ---- LO weight fragments -> LDS [kt][wv][lane][8] (lane-linear) ----
    for (int f = tid; f < 2560; f += 256){
        int kt = f >> 8, wv2 = (f >> 6) & 3, ll = f & 63;
        int c2 = ll & 15, ks2 = ll >> 4;
        int G2 = (c2&3)*HH + ubase + wv2*4 + (c2>>2);
        int kk = kt*32 + ks2*8;
        const float* p = (kk < 64) ? (Wih0 + (size_t)G2*DIN + kk)
                                   : (Whh0 + (size_t)G2*HH + (kk - 64));
        bf16x8 hi_, lo_; split8(*(const float4*)p, *(const float4*)(p+4), hi_, lo_);
        *(bf16x8*)(sh + OFF_W0LO + f*8) = lo_;
    }
    for (int f = tid; f < 4096; f += 256){
        int kt = f >> 8, wv2 = (f >> 6) & 3, ll = f & 63;
        int c2 = ll & 15, ks2 = ll >> 4;
        int G2 = (c2&3)*HH + ubase + wv2*4 + (c2>>2);
        int kk = kt*32 + ks2*8;
        const float* p = (kk < 256) ? (Wih1 + (size_t)G2*HH + kk)
                                    : (Whh1 + (size_t)G2*HH + (kk - 256));
        bf16x8 hi_, lo_; split8(*(const float4*)p, *(const float4*)(p+4), hi_, lo_);
        *(bf16x8*)(sh + OFF_W1LO + f*8) = lo_;
    }

    // ---- zero my WG's published h slots (16 rows x 16 units x 4 planes x 2 par) ----
    #pragma unroll
    for (int j = 0; j < 8; ++j){
        int cid = tid + j*256;                 // 0..2047
        int pp = cid >> 8;                     // plane*2 + parity
        int idx = cid & 255;
        int row = idx >> 4, vu = idx & 15;
        hb[(size_t)(pp>>1)*131072 + (pp&1)*65536
           + (size_t)(grpbase + row)*HH + ubase + vu] = 0;
    }
    // ---- stage x(0) into parity 0 (swizzled) ----
    if (tid < 128){
        int r = tid >> 3, k8 = tid & 7;
        const float* xp = x + (size_t)(grpbase + r)*(TT*DIN) + k8*8;
        bf16x8 xh, xl; split8(*(const float4*)xp, *(const float4*)(xp+4), xh, xl);
        short* d = sh + OFF_X + r*64 + ((k8 ^ (r&7)) << 3);
        *(bf16x8*)d = xh;
        *(bf16x8*)(d + 1024) = xl;
    }
    group_barrier(flg, wgin, 1u);

    float cs0[4] = {0.f,0.f,0.f,0.f};
    float cs1[4] = {0.f,0.f,0.f,0.f};

    for (int k = 0; k <= TT; ++k){
        // ---- stage h0(k-1), h1(k-2): 8 x uint4 per thread, cached reads ----
        {
            const unsigned rdo = ((k + 1) & 1) * 65536u;
            #pragma unroll
            for (int j = 0; j < 8; ++j){
                int cid = tid + j*256;             // 0..2047
                int p = cid >> 9, idx = cid & 511;
                int row = idx >> 5, slot = idx & 31;
                const u16* src = hb + (size_t)p*131072 + rdo
                               + (size_t)(grpbase + row)*HH + slot*8;
                *(u32x4*)(sh + OFF_H + p*4096 + row*256 + ((slot ^ (row&7)) << 3))
                    = *(const u32x4*)src;
            }
        }
        __syncthreads();

        // ---- phase A: layer0 step t=k ----
        if (k < TT){
            f32x4 ac[4] = {};
            const short* xb  = sh + OFF_X + (k&1)*2048 + c*64;
            const short* h0r = sh + OFF_H + c*256;
            #pragma unroll
            for (int kt = 0; kt < 10; ++kt){
                bf16x8 ah, al;
                if (kt < 2){
                    int s = ((kt*4 + ks) ^ cx) << 3;
                    ah = *(const bf16x8*)(xb + s);
                    al = *(const bf16x8*)(xb + 1024 + s);
                } else {
                    int s = (((kt-2)*4 + ks) ^ cx) << 3;
                    ah = *(const bf16x8*)(h0r + s);
                    al = *(const bf16x8*)(h0r + 4096 + s);
                }
                bf16x8 wl = *(const bf16x8*)(sh + OFF_W0LO + (kt*4 + wv)*512 + l*8);
                const int q = kt & 3;
                ac[q] = MFMA16(ah, w0h[kt], ac[q]);
                ac[q] = MFMA16(al, w0h[kt], ac[q]);
                ac[q] = MFMA16(ah, wl,      ac[q]);
            }
            f32x4 aa = (ac[0] + ac[1]) + (ac[2] + ac[3]);
            const unsigned wro = (k & 1) * 65536u;
            #pragma unroll
            for (int j = 0; j < 4; ++j){
                float vv = aa[j] + bs0;
                float gi, gf, gg, go; gates4(b, vv, gi, gf, gg, go);
                cs0[j] = sigf(gf)*cs0[j] + sigf(gi)*tanh_fast(gg);
                float hn = sigf(go)*tanh_fast(cs0[j]);
                if (b == 0){
                    u16 hh_ = f2bf(hn);
                    u16 hl_ = f2bf(hn - bf2f(hh_));
                    size_t po = (size_t)(grpbase + ks*4 + j)*HH + un;
                    (hb + wro)[po]          = hh_;
                    (hb + 131072 + wro)[po] = hl_;
                }
            }
        }
        // ---- phase B: layer1 step t=k-1 ----
        if (k >= 1){
            f32x4 ac[4] = {};
            const short* h0r = sh + OFF_H + c*256;
            const short* h1r = sh + OFF_H + 8192 + c*256;
            #pragma unroll
            for (int kt = 0; kt < 16; ++kt){
                bf16x8 ah, al;
                if (kt < 8){
                    int s = ((kt*4 + ks) ^ cx) << 3;
                    ah = *(const bf16x8*)(h0r + s);
                    al = *(const bf16x8*)(h0r + 4096 + s);
                } else {
                    int s = (((kt-8)*4 + ks) ^ cx) << 3;
                    ah = *(const bf16x8*)(h1r + s);
                    al = *(const bf16x8*)(h1r + 4096 + s);
                }
                bf16x8 wl = *(const bf16x8*)(sh + OFF_W1LO + (kt*4 + wv)*512 + l*8);
                const int q = kt & 3;
                ac[q] = MFMA16(ah, w1h[kt], ac[q]);
                ac[q] = MFMA16(al, w1h[kt], ac[q]);
                ac[q] = MFMA16(ah, wl,      ac[q]);
            }
            f32x4 aa = (ac[0] + ac[1]) + (ac[2] + ac[3]);
            const unsigned wro = (k & 1) * 65536u;
            #pragma unroll
            for (int j = 0; j < 4; ++j){
                float vv = aa[j] + bs1;
                float gi, gf, gg, go; gates4(b, vv, gi, gf, gg, go);
                cs1[j] = sigf(gf)*cs1[j] + sigf(gi)*tanh_fast(gg);
                float hn = sigf(go)*tanh_fast(cs1[j]);
                if (b == 0){
                    u16 hh_ = f2bf(hn);
                    u16 hl_ = f2bf(hn - bf2f(hh_));
                    size_t po = (size_t)(grpbase + ks*4 + j)*HH + un;
                    (hb + 262144 + wro)[po] = hh_;
                    (hb + 393216 + wro)[po] = hl_;
                }
            }
        }
        // ---- prefetch-stage x(k+1) (dbuf parity) ----
        if (k + 1 < TT && tid < 128){
            int r = tid >> 3, k8 = tid & 7;
            const float* xp = x + (size_t)(grpbase + r)*(TT*DIN) + (size_t)(k+1)*DIN + k8*8;
            bf16x8 xh, xl; split8(*(const float4*)xp, *(const float4*)(xp+4), xh, xl);
            short* d = sh + OFF_X + ((k+1)&1)*2048 + r*64 + ((k8 ^ (r&7)) << 3);
            *(bf16x8*)d = xh;
            *(bf16x8*)(d + 1024) = xl;
        }
        group_barrier(flg, wgin, (unsigned)(k + 2));
    }

    // ---- dense head: out = h1(T-1) @ Wd^T + bd ; h1(T-1) in parity-0 planes ----
    if (wgin == 0 && tid < 32){
        int r = tid >> 1, j = tid & 1;
        const u16* hhp = hb + 262144 + (size_t)(grpbase + r)*HH;
        const u16* hlp = hb + 393216 + (size_t)(grpbase + r)*HH;
        const float* wdp = Wd + j*HH;
        float a = bd[j];
        #pragma unroll 4
        for (int q = 0; q < HH; ++q)
            a += (bf2f(hhp[q]) + bf2f(hlp[q])) * wdp[q];
        out[(grpbase + r)*2 + j] = a;
    }
}

extern "C" void kernel_launch(void* const* d_in, const int* in_sizes, int n_in,
                              void* d_out, int out_size, void* d_ws, size_t ws_size,
                              hipStream_t stream) {
    const float* x    = (const float*)d_in[0];
    const float* Wih0 = (const float*)d_in[1];
    const float* Whh0 = (const float*)d_in[2];
    const float* bih0 = (const float*)d_in[3];
    const float* bhh0 = (const float*)d_in[4];
    const float* Wih1 = (const float*)d_in[5];
    const float* Whh1 = (const float*)d_in[6];
    const float* bih1 = (const float*)d_in[7];
    const float* bhh1 = (const float*)d_in[8];
    const float* Wd   = (const float*)d_in[9];
    const float* bd   = (const float*)d_in[10];
    float* out = (float*)d_out;

    u32t* flags = (u32t*)d_ws;                     // 16 groups x 16 slots x 64B
    u16* hb = (u16*)((char*)d_ws + 32768);         // 1 MB h hi/lo planes

    hipMemsetAsync(d_ws, 0, 32768, stream);

    hipFuncSetAttribute((const void*)lstm_v9,
                        hipFuncAttributeMaxDynamicSharedMemorySize, LDS_BYTES);

    lstm_v9<<<dim3(256), dim3(256), LDS_BYTES, stream>>>(
        x, Wih0, Whh0, bih0, bhh0, Wih1, Whh1, bih1, bhh1,
        Wd, bd, out, hb, flags);
}